// Round 15
// baseline (183.499 us; speedup 1.0000x reference)
//
#include <hip/hip_runtime.h>
#include <hip/hip_bf16.h>

static constexpr int KC   = 9;    // kernel bins
static constexpr int CIN  = 32;   // input channels
static constexpr int CA   = 24;   // branch-a out channels
static constexpr int CB   = 8;    // branch-b out channels
static constexpr int COUT = 32;   // CA + CB
static constexpr int KCC  = KC * CIN;       // 288
static constexpr int SPP  = 2 * KCC;        // 576 bf16 S entries per point

// ---------------------------------------------------------------------------
// Prep: CSR row pointer + per-edge importance pre-gather + W pack, one launch.
// ---------------------------------------------------------------------------
__global__ void prep(const int* __restrict__ oidx, const int* __restrict__ nidx,
                     const float* __restrict__ importance,
                     const float* __restrict__ Wa, const float* __restrict__ Wb,
                     int* __restrict__ rp, float* __restrict__ imp_e,
                     float* __restrict__ Wc, int E, int nout) {
    int e = blockIdx.x * blockDim.x + threadIdx.x;
    if (e < E) {
        int cur  = oidx[e];
        int prev = (e == 0) ? -1 : oidx[e - 1];
        for (int id = prev + 1; id <= cur; ++id) rp[id] = e;
        if (e == E - 1) {
            for (int id = cur + 1; id <= nout; ++id) rp[id] = E;
        }
        imp_e[e] = importance[nidx[e]];
        if (e < KCC * COUT) {
            int f  = e & (COUT - 1);
            int kc = e >> 5;
            Wc[e] = (f < CA) ? Wa[kc * CA + f] : Wb[kc * CB + (f - CA)];
        }
    }
}

// uniform-q conditional add, TERNARY TREE: q in SGPR -> <=4 scalar branches
// per edge (was a <=9-deep linear chain). One v_add executed per edge.
#define ACC_ADD(Q, V)                                          \
    do {                                                       \
        if ((Q) < 3) {                                         \
            if      ((Q) == 0) acc[0] += (V);                  \
            else if ((Q) == 1) acc[1] += (V);                  \
            else               acc[2] += (V);                  \
        } else if ((Q) < 6) {                                  \
            if      ((Q) == 3) acc[3] += (V);                  \
            else if ((Q) == 4) acc[4] += (V);                  \
            else               acc[5] += (V);                  \
        } else {                                               \
            if      ((Q) == 6) acc[6] += (V);                  \
            else if ((Q) == 7) acc[7] += (V);                  \
            else               acc[8] += (V);                  \
        }                                                      \
    } while (0)

// ---------------------------------------------------------------------------
// Kernel A: scalar-q register accumulation (round-11 champion structure:
// grid-stride wave per point, self-balancing), with 4-edge unroll for MLP.
// c = lane&31 (channel), h = lane>>5 (branch: 0->Sa v=f, 1->Sb v=f*m).
// All per-edge metadata wave-uniform (s_load); feats gather is the only
// vector load. Clamp+zero masking, no tail loop. bf16 flush stores.
// ---------------------------------------------------------------------------
__global__ __launch_bounds__(256) void accum_x(
    const float* __restrict__ feats, const float* __restrict__ imp_e,
    const int* __restrict__ nidx, const int* __restrict__ nkidx,
    const int* __restrict__ rp,
    __hip_bfloat16* __restrict__ S, float* __restrict__ impAcc, int nout)
{
    const int lane = threadIdx.x & 63;
    const int c    = lane & 31;
    const int h    = lane >> 5;
    int gw = (blockIdx.x * 256 + threadIdx.x) >> 6;
    gw = __builtin_amdgcn_readfirstlane(gw);          // uniform wave id
    const int NW = (gridDim.x * 256) >> 6;

    for (int n = gw; n < nout; n += NW) {
        const int start = rp[n];                      // uniform
        const int end   = rp[n + 1];                  // uniform

        float acc[KC];
#pragma unroll
        for (int k = 0; k < KC; ++k) acc[k] = 0.f;
        float accImp = 0.f;

        for (int e = start; e < end; e += 4) {
            const int last = end - 1;
            int e1 = (e + 1 < end) ? e + 1 : last;
            int e2 = (e + 2 < end) ? e + 2 : last;
            int e3 = (e + 3 < end) ? e + 3 : last;
            // metadata (uniform -> s_load, sequential lines)
            int q0 = __builtin_amdgcn_readfirstlane(nkidx[e]);
            int q1 = __builtin_amdgcn_readfirstlane(nkidx[e1]);
            int q2 = __builtin_amdgcn_readfirstlane(nkidx[e2]);
            int q3 = __builtin_amdgcn_readfirstlane(nkidx[e3]);
            int i0 = nidx[e], i1 = nidx[e1], i2 = nidx[e2], i3 = nidx[e3];
            float m0 = imp_e[e], m1 = imp_e[e1], m2 = imp_e[e2], m3 = imp_e[e3];
            // 4 independent coalesced 128B row gathers in flight
            float f0 = feats[(size_t)i0 * CIN + c];
            float f1 = feats[(size_t)i1 * CIN + c];
            float f2 = feats[(size_t)i2 * CIN + c];
            float f3 = feats[(size_t)i3 * CIN + c];
            // mask clamped (invalid) edges - data, not control flow
            if (e + 1 >= end) { f1 = 0.f; m1 = 0.f; }
            if (e + 2 >= end) { f2 = 0.f; m2 = 0.f; }
            if (e + 3 >= end) { f3 = 0.f; m3 = 0.f; }
            accImp += (m0 + m1) + (m2 + m3);
            float v0 = h ? f0 * m0 : f0;
            float v1 = h ? f1 * m1 : f1;
            float v2 = h ? f2 * m2 : f2;
            float v3 = h ? f3 * m3 : f3;
            ACC_ADD(q0, v0);
            ACC_ADD(q1, v1);
            ACC_ADD(q2, v2);
            ACC_ADD(q3, v3);
        }

        // flush: one wave-wide bf16 store per k (h selects Sa/Sb region)
        __hip_bfloat16* Sp = S + (size_t)n * SPP + h * KCC + c;
#pragma unroll
        for (int k = 0; k < KC; ++k) Sp[k * CIN] = __float2bfloat16(acc[k]);
        if (lane == 0) impAcc[n] = accImp;
    }
}
#undef ACC_ADD

// ---------------------------------------------------------------------------
// Kernel B: lane-per-point epilogue (round-10/11 winner), bf16 S input.
// W addresses wave-uniform -> s_load through K$; S per-lane row stream.
// ---------------------------------------------------------------------------
__global__ __launch_bounds__(256) void epilogue_g(
    const __hip_bfloat16* __restrict__ S, const float* __restrict__ impAcc,
    const float* __restrict__ Wc, const float* __restrict__ ba,
    const float* __restrict__ bb,
    float* __restrict__ outf, float* __restrict__ outimp, int nout)
{
    const int gtid   = blockIdx.x * 256 + threadIdx.x;
    const bool valid = (gtid < nout);
    const int n      = valid ? gtid : (nout - 1);

    const unsigned short* Sp =
        reinterpret_cast<const unsigned short*>(S + (size_t)n * SPP);

    float acc[COUT];
#pragma unroll
    for (int j = 0; j < COUT; ++j) acc[j] = 0.f;

    for (int t = 0; t < KCC; t += 8) {
        uint4 ua = *reinterpret_cast<const uint4*>(Sp + t);
        uint4 ub = *reinterpret_cast<const uint4*>(Sp + KCC + t);
        unsigned int uaw[4] = {ua.x, ua.y, ua.z, ua.w};
        unsigned int ubw[4] = {ub.x, ub.y, ub.z, ub.w};
        float sav[8], sbv[8];
#pragma unroll
        for (int p = 0; p < 4; ++p) {
            sav[2 * p]     = __uint_as_float(uaw[p] << 16);
            sav[2 * p + 1] = __uint_as_float(uaw[p] & 0xffff0000u);
            sbv[2 * p]     = __uint_as_float(ubw[p] << 16);
            sbv[2 * p + 1] = __uint_as_float(ubw[p] & 0xffff0000u);
        }
#pragma unroll
        for (int u = 0; u < 8; ++u) {
            const float* w = Wc + (t + u) * COUT;   // wave-uniform -> s_load
#pragma unroll
            for (int j = 0; j < CA; ++j) acc[j] = fmaf(sav[u], w[j], acc[j]);
#pragma unroll
            for (int j = 0; j < CB; ++j)
                acc[CA + j] = fmaf(sbv[u], w[CA + j], acc[CA + j]);
        }
    }

    float impTot = impAcc[n];
    float denom  = impTot > 0.f ? impTot : 1.f;

    if (valid) {
        float res[COUT];
#pragma unroll
        for (int j = 0; j < CA; ++j) res[j] = fmaxf(acc[j] + ba[j], 0.f);
#pragma unroll
        for (int j = 0; j < CB; ++j)
            res[CA + j] = fmaxf(acc[CA + j] / denom + bb[j], 0.f);
        float4* op = reinterpret_cast<float4*>(outf + (size_t)n * COUT);
#pragma unroll
        for (int j4 = 0; j4 < 8; ++j4)
            op[j4] = make_float4(res[4 * j4], res[4 * j4 + 1],
                                 res[4 * j4 + 2], res[4 * j4 + 3]);
        outimp[n] = impTot;
    }
}

// ===========================================================================
// Fallback (round-6 fused kernel) if ws can't hold the scratch.
// ===========================================================================
static constexpr int WSTR = KC * CIN + 4;
static constexpr int PPB = 16;
static constexpr int TPB = 512;
static constexpr int NHW = TPB / 32;

__global__ void build_rowptr_fb(const int* __restrict__ oidx, int* __restrict__ rp,
                                int E, int nout) {
    int e = blockIdx.x * blockDim.x + threadIdx.x;
    if (e >= E) return;
    int cur  = oidx[e];
    int prev = (e == 0) ? -1 : oidx[e - 1];
    for (int id = prev + 1; id <= cur; ++id) rp[id] = e;
    if (e == E - 1) {
        for (int id = cur + 1; id <= nout; ++id) rp[id] = E;
    }
}

__global__ void pack_weights_fkc(const float* __restrict__ Wa,
                                 const float* __restrict__ Wb,
                                 float* __restrict__ Wt) {
    int t = blockIdx.x * blockDim.x + threadIdx.x;
    if (t >= COUT * KC * CIN) return;
    int f = t / (KC * CIN);
    int r = t % (KC * CIN);
    Wt[t] = (f < CA) ? Wa[r * CA + f] : Wb[r * CB + (f - CA)];
}

__global__ __launch_bounds__(TPB) void fused_block(
    const float* __restrict__ feats, const float* __restrict__ importance,
    const float* __restrict__ Wt, const float* __restrict__ ba,
    const float* __restrict__ bb,
    const int* __restrict__ nidx, const int* __restrict__ nkidx,
    const int* __restrict__ noidx, const int* __restrict__ rp,
    float* __restrict__ outf, float* __restrict__ outimp, int nout)
{
    __shared__ __align__(16) float sW[COUT * WSTR];
    __shared__ __align__(16) float sS[PPB][2][KC * CIN];
    __shared__ float sImp[PPB];

    const int tid = threadIdx.x;
    const int hw  = tid >> 5;
    const int c   = tid & 31;
    const int p0  = blockIdx.x * PPB;

    {
        float* pS = &sS[0][0][0];
        for (int i = tid; i < PPB * 2 * KC * CIN; i += TPB) pS[i] = 0.f;
        for (int i = tid; i < COUT * KC * CIN; i += TPB) {
            int f = i / (KC * CIN);
            int r = i % (KC * CIN);
            sW[f * WSTR + r] = Wt[i];
        }
        if (tid < PPB) sImp[tid] = 0.f;
    }
    __syncthreads();

    const int pend   = (p0 + PPB < nout) ? (p0 + PPB) : nout;
    const int estart = rp[p0];
    const int eend   = rp[pend];
    const int cnt    = eend - estart;
    const int per    = (cnt + NHW - 1) / NHW;
    int a = estart + hw * per;
    int b = a + per; if (b > eend) b = eend;

    float* S0 = &sS[0][0][0];
    for (int e = a; e < b; ++e) {
        int   n0 = noidx[e], i0 = nidx[e], q0 = nkidx[e];
        float m0 = importance[i0];
        float f0 = feats[(size_t)i0 * CIN + c];
        float* bp = S0 + (n0 - p0) * (2 * KC * CIN) + q0 * CIN + c;
        atomicAdd(bp, f0);
        atomicAdd(bp + KC * CIN, f0 * m0);
        if (c == 0) atomicAdd(&sImp[n0 - p0], m0);
    }
    __syncthreads();

    const int wave = tid >> 6;
    const int lane = tid & 63;
    const int f    = lane & 31;
    const int h    = lane >> 5;
#pragma unroll
    for (int rep = 0; rep < 2; ++rep) {
        const int slot = wave * 2 + rep;
        const int n    = p0 + slot;
        if (n >= nout) break;
        float impTot = sImp[slot];
        float denom  = impTot > 0.f ? impTot : 1.f;
        const float* Sbase = &sS[slot][(f < CA) ? 0 : 1][0];
        const float* Wbase = sW + f * WSTR;
        float acc = 0.f;
#pragma unroll
        for (int k = 0; k < KC; ++k) {
            int off = k * CIN + h * 16;
#pragma unroll
            for (int j = 0; j < 16; ++j) acc = fmaf(Sbase[off + j], Wbase[off + j], acc);
        }
        float tot = acc + __shfl_xor(acc, 32, 64);
        if (h == 0) {
            float res = (f < CA) ? (tot + ba[f]) : (tot / denom + bb[f - CA]);
            outf[(size_t)n * COUT + f] = fmaxf(res, 0.f);
        }
        if (lane == 0) outimp[n] = impTot;
    }
}

// ---------------------------------------------------------------------------
extern "C" void kernel_launch(void* const* d_in, const int* in_sizes, int n_in,
                              void* d_out, int out_size, void* d_ws, size_t ws_size,
                              hipStream_t stream) {
    const float* feats      = (const float*)d_in[0];
    const float* importance = (const float*)d_in[1];
    const float* Wa         = (const float*)d_in[2];
    const float* ba         = (const float*)d_in[3];
    const float* Wb         = (const float*)d_in[4];
    const float* bb         = (const float*)d_in[5];
    const int*   nidx       = (const int*)d_in[6];
    const int*   nkidx      = (const int*)d_in[7];
    const int*   noidx      = (const int*)d_in[8];

    const int E    = in_sizes[6];
    const int nout = out_size / (COUT + 1);

    float* outf   = (float*)d_out;
    float* outimp = outf + (size_t)nout * COUT;

    // ws: S bf16 [nout*576] | impAcc [nout] | Wc [288*32] | rp [nout+1] | imp_e [E]
    const size_t off_imp = ((size_t)nout * SPP * sizeof(__hip_bfloat16) + 255) & ~(size_t)255;
    const size_t off_wc  = (off_imp + (size_t)nout * sizeof(float) + 255) & ~(size_t)255;
    const size_t off_rp  = (off_wc + (size_t)KCC * COUT * sizeof(float) + 255) & ~(size_t)255;
    const size_t off_ie  = (off_rp + (size_t)(nout + 1) * sizeof(int) + 255) & ~(size_t)255;
    const size_t need    = off_ie + (size_t)E * sizeof(float);

    if (ws_size >= need) {
        __hip_bfloat16* S = (__hip_bfloat16*)d_ws;
        float* impAcc = (float*)((char*)d_ws + off_imp);
        float* Wc     = (float*)((char*)d_ws + off_wc);
        int*   rp     = (int*)((char*)d_ws + off_rp);
        float* imp_e  = (float*)((char*)d_ws + off_ie);

        prep<<<(E + 255) / 256, 256, 0, stream>>>(
            noidx, nidx, importance, Wa, Wb, rp, imp_e, Wc, E, nout);
        accum_x<<<2048, 256, 0, stream>>>(
            feats, imp_e, nidx, nkidx, rp, S, impAcc, nout);
        epilogue_g<<<(nout + 255) / 256, 256, 0, stream>>>(
            S, impAcc, Wc, ba, bb, outf, outimp, nout);
    } else {
        int*   rp = (int*)d_ws;
        size_t rp_bytes = ((size_t)(nout + 1) * sizeof(int) + 255) & ~(size_t)255;
        float* Wt = (float*)((char*)d_ws + rp_bytes);

        build_rowptr_fb<<<(E + 255) / 256, 256, 0, stream>>>(noidx, rp, E, nout);
        pack_weights_fkc<<<(COUT * KC * CIN + 255) / 256, 256, 0, stream>>>(Wa, Wb, Wt);
        fused_block<<<(nout + PPB - 1) / PPB, TPB, 0, stream>>>(
            feats, importance, Wt, ba, bb, nidx, nkidx, noidx, rp,
            outf, outimp, nout);
    }
}

// Round 16
// 132.727 us; speedup vs baseline: 1.3825x; 1.3825x over previous
//
#include <hip/hip_runtime.h>
#include <hip/hip_bf16.h>

static constexpr int KC   = 9;    // kernel bins
static constexpr int CIN  = 32;   // input channels
static constexpr int CA   = 24;   // branch-a out channels
static constexpr int CB   = 8;    // branch-b out channels
static constexpr int COUT = 32;   // CA + CB
static constexpr int KCC  = KC * CIN;       // 288
static constexpr int SPP  = 2 * KCC;        // 576 bf16 S entries per point

// ---------------------------------------------------------------------------
// Prep: CSR row pointer + per-edge importance pre-gather + W pack, one launch.
// ---------------------------------------------------------------------------
__global__ void prep(const int* __restrict__ oidx, const int* __restrict__ nidx,
                     const float* __restrict__ importance,
                     const float* __restrict__ Wa, const float* __restrict__ Wb,
                     int* __restrict__ rp, float* __restrict__ imp_e,
                     float* __restrict__ Wc, int E, int nout) {
    int e = blockIdx.x * blockDim.x + threadIdx.x;
    if (e < E) {
        int cur  = oidx[e];
        int prev = (e == 0) ? -1 : oidx[e - 1];
        for (int id = prev + 1; id <= cur; ++id) rp[id] = e;
        if (e == E - 1) {
            for (int id = cur + 1; id <= nout; ++id) rp[id] = E;
        }
        imp_e[e] = importance[nidx[e]];
        if (e < KCC * COUT) {
            int f  = e & (COUT - 1);
            int kc = e >> 5;
            Wc[e] = (f < CA) ? Wa[kc * CA + f] : Wb[kc * CB + (f - CA)];
        }
    }
}

// uniform-q conditional add (round-11's measured-best linear scalar chain)
#define ACC_ADD(Q, V)                              \
    do {                                           \
        if      ((Q) == 0) acc[0] += (V);          \
        else if ((Q) == 1) acc[1] += (V);          \
        else if ((Q) == 2) acc[2] += (V);          \
        else if ((Q) == 3) acc[3] += (V);          \
        else if ((Q) == 4) acc[4] += (V);          \
        else if ((Q) == 5) acc[5] += (V);          \
        else if ((Q) == 6) acc[6] += (V);          \
        else if ((Q) == 7) acc[7] += (V);          \
        else               acc[8] += (V);          \
    } while (0)

__device__ __forceinline__ float readlane_f(float v, int l) {
    return __uint_as_float(__builtin_amdgcn_readlane(__float_as_uint(v), l));
}

// ---------------------------------------------------------------------------
// Kernel A: VECTOR-path metadata + scalar-chain accumulate.
// Round-11 champion structure (grid-stride wave per point, self-balancing,
// 4-edge group). KEY CHANGE vs accum_u: metadata is loaded through the
// vector memory path (lane l reads edge e+(l&3): 3 vector loads per 4 edges,
// L1-hit sequential 16B lines, vmcnt-overlapped) instead of 12 s_loads via
// the narrow shared scalar/K$ path; values are moved to SGPRs afterward
// with v_readlane. Feats gather + branch chain unchanged from round 11.
// ---------------------------------------------------------------------------
__global__ __launch_bounds__(256) void accum_y(
    const float* __restrict__ feats, const float* __restrict__ imp_e,
    const int* __restrict__ nidx, const int* __restrict__ nkidx,
    const int* __restrict__ rp,
    __hip_bfloat16* __restrict__ S, float* __restrict__ impAcc, int nout)
{
    const int lane = threadIdx.x & 63;
    const int c    = lane & 31;
    const int h    = lane >> 5;
    const int l4   = lane & 3;
    int gw = (blockIdx.x * 256 + threadIdx.x) >> 6;
    gw = __builtin_amdgcn_readfirstlane(gw);          // uniform wave id
    const int NW = (gridDim.x * 256) >> 6;

    for (int n = gw; n < nout; n += NW) {
        const int start = rp[n];                      // uniform
        const int end   = rp[n + 1];                  // uniform

        float acc[KC];
#pragma unroll
        for (int k = 0; k < KC; ++k) acc[k] = 0.f;
        float accImp = 0.f;

        for (int e = start; e < end; e += 4) {
            // per-lane metadata edge (clamped); 16B-line vector loads
            int em = e + l4;
            if (em > end - 1) em = end - 1;
            int   metaI = nidx[em];
            int   metaQ = nkidx[em];
            float metaM = imp_e[em];

            // move to SGPRs (v_readlane, exec-independent)
            int q0 = __builtin_amdgcn_readlane(metaQ, 0);
            int q1 = __builtin_amdgcn_readlane(metaQ, 1);
            int q2 = __builtin_amdgcn_readlane(metaQ, 2);
            int q3 = __builtin_amdgcn_readlane(metaQ, 3);
            int i0 = __builtin_amdgcn_readlane(metaI, 0);
            int i1 = __builtin_amdgcn_readlane(metaI, 1);
            int i2 = __builtin_amdgcn_readlane(metaI, 2);
            int i3 = __builtin_amdgcn_readlane(metaI, 3);
            float m0 = readlane_f(metaM, 0);
            float m1 = readlane_f(metaM, 1);
            float m2 = readlane_f(metaM, 2);
            float m3 = readlane_f(metaM, 3);

            // 4 independent coalesced 128B row gathers in flight
            float f0 = feats[(size_t)i0 * CIN + c];
            float f1 = feats[(size_t)i1 * CIN + c];
            float f2 = feats[(size_t)i2 * CIN + c];
            float f3 = feats[(size_t)i3 * CIN + c];

            // mask clamped (invalid) edges - uniform conditions, data masking
            if (e + 1 >= end) { f1 = 0.f; m1 = 0.f; }
            if (e + 2 >= end) { f2 = 0.f; m2 = 0.f; }
            if (e + 3 >= end) { f3 = 0.f; m3 = 0.f; }
            accImp += (m0 + m1) + (m2 + m3);

            // half 1 weights by importance: v = f * (h ? m : 1)
            float v0 = f0 * (h ? m0 : 1.0f);
            float v1 = f1 * (h ? m1 : 1.0f);
            float v2 = f2 * (h ? m2 : 1.0f);
            float v3 = f3 * (h ? m3 : 1.0f);
            ACC_ADD(q0, v0);
            ACC_ADD(q1, v1);
            ACC_ADD(q2, v2);
            ACC_ADD(q3, v3);
        }

        // flush: one wave-wide bf16 store per k (h selects Sa/Sb region)
        __hip_bfloat16* Sp = S + (size_t)n * SPP + h * KCC + c;
#pragma unroll
        for (int k = 0; k < KC; ++k) Sp[k * CIN] = __float2bfloat16(acc[k]);
        if (lane == 0) impAcc[n] = accImp;
    }
}
#undef ACC_ADD

// ---------------------------------------------------------------------------
// Kernel B: lane-per-point epilogue (round-10/11 winner), bf16 S input.
// W addresses wave-uniform -> s_load through K$; S per-lane row stream.
// ---------------------------------------------------------------------------
__global__ __launch_bounds__(256) void epilogue_g(
    const __hip_bfloat16* __restrict__ S, const float* __restrict__ impAcc,
    const float* __restrict__ Wc, const float* __restrict__ ba,
    const float* __restrict__ bb,
    float* __restrict__ outf, float* __restrict__ outimp, int nout)
{
    const int gtid   = blockIdx.x * 256 + threadIdx.x;
    const bool valid = (gtid < nout);
    const int n      = valid ? gtid : (nout - 1);

    const unsigned short* Sp =
        reinterpret_cast<const unsigned short*>(S + (size_t)n * SPP);

    float acc[COUT];
#pragma unroll
    for (int j = 0; j < COUT; ++j) acc[j] = 0.f;

    for (int t = 0; t < KCC; t += 8) {
        uint4 ua = *reinterpret_cast<const uint4*>(Sp + t);
        uint4 ub = *reinterpret_cast<const uint4*>(Sp + KCC + t);
        unsigned int uaw[4] = {ua.x, ua.y, ua.z, ua.w};
        unsigned int ubw[4] = {ub.x, ub.y, ub.z, ub.w};
        float sav[8], sbv[8];
#pragma unroll
        for (int p = 0; p < 4; ++p) {
            sav[2 * p]     = __uint_as_float(uaw[p] << 16);
            sav[2 * p + 1] = __uint_as_float(uaw[p] & 0xffff0000u);
            sbv[2 * p]     = __uint_as_float(ubw[p] << 16);
            sbv[2 * p + 1] = __uint_as_float(ubw[p] & 0xffff0000u);
        }
#pragma unroll
        for (int u = 0; u < 8; ++u) {
            const float* w = Wc + (t + u) * COUT;   // wave-uniform -> s_load
#pragma unroll
            for (int j = 0; j < CA; ++j) acc[j] = fmaf(sav[u], w[j], acc[j]);
#pragma unroll
            for (int j = 0; j < CB; ++j)
                acc[CA + j] = fmaf(sbv[u], w[CA + j], acc[CA + j]);
        }
    }

    float impTot = impAcc[n];
    float denom  = impTot > 0.f ? impTot : 1.f;

    if (valid) {
        float res[COUT];
#pragma unroll
        for (int j = 0; j < CA; ++j) res[j] = fmaxf(acc[j] + ba[j], 0.f);
#pragma unroll
        for (int j = 0; j < CB; ++j)
            res[CA + j] = fmaxf(acc[CA + j] / denom + bb[j], 0.f);
        float4* op = reinterpret_cast<float4*>(outf + (size_t)n * COUT);
#pragma unroll
        for (int j4 = 0; j4 < 8; ++j4)
            op[j4] = make_float4(res[4 * j4], res[4 * j4 + 1],
                                 res[4 * j4 + 2], res[4 * j4 + 3]);
        outimp[n] = impTot;
    }
}

// ===========================================================================
// Fallback (round-6 fused kernel) if ws can't hold the scratch.
// ===========================================================================
static constexpr int WSTR = KC * CIN + 4;
static constexpr int PPB = 16;
static constexpr int TPB = 512;
static constexpr int NHW = TPB / 32;

__global__ void build_rowptr_fb(const int* __restrict__ oidx, int* __restrict__ rp,
                                int E, int nout) {
    int e = blockIdx.x * blockDim.x + threadIdx.x;
    if (e >= E) return;
    int cur  = oidx[e];
    int prev = (e == 0) ? -1 : oidx[e - 1];
    for (int id = prev + 1; id <= cur; ++id) rp[id] = e;
    if (e == E - 1) {
        for (int id = cur + 1; id <= nout; ++id) rp[id] = E;
    }
}

__global__ void pack_weights_fkc(const float* __restrict__ Wa,
                                 const float* __restrict__ Wb,
                                 float* __restrict__ Wt) {
    int t = blockIdx.x * blockDim.x + threadIdx.x;
    if (t >= COUT * KC * CIN) return;
    int f = t / (KC * CIN);
    int r = t % (KC * CIN);
    Wt[t] = (f < CA) ? Wa[r * CA + f] : Wb[r * CB + (f - CA)];
}

__global__ __launch_bounds__(TPB) void fused_block(
    const float* __restrict__ feats, const float* __restrict__ importance,
    const float* __restrict__ Wt, const float* __restrict__ ba,
    const float* __restrict__ bb,
    const int* __restrict__ nidx, const int* __restrict__ nkidx,
    const int* __restrict__ noidx, const int* __restrict__ rp,
    float* __restrict__ outf, float* __restrict__ outimp, int nout)
{
    __shared__ __align__(16) float sW[COUT * WSTR];
    __shared__ __align__(16) float sS[PPB][2][KC * CIN];
    __shared__ float sImp[PPB];

    const int tid = threadIdx.x;
    const int hw  = tid >> 5;
    const int c   = tid & 31;
    const int p0  = blockIdx.x * PPB;

    {
        float* pS = &sS[0][0][0];
        for (int i = tid; i < PPB * 2 * KC * CIN; i += TPB) pS[i] = 0.f;
        for (int i = tid; i < COUT * KC * CIN; i += TPB) {
            int f = i / (KC * CIN);
            int r = i % (KC * CIN);
            sW[f * WSTR + r] = Wt[i];
        }
        if (tid < PPB) sImp[tid] = 0.f;
    }
    __syncthreads();

    const int pend   = (p0 + PPB < nout) ? (p0 + PPB) : nout;
    const int estart = rp[p0];
    const int eend   = rp[pend];
    const int cnt    = eend - estart;
    const int per    = (cnt + NHW - 1) / NHW;
    int a = estart + hw * per;
    int b = a + per; if (b > eend) b = eend;

    float* S0 = &sS[0][0][0];
    for (int e = a; e < b; ++e) {
        int   n0 = noidx[e], i0 = nidx[e], q0 = nkidx[e];
        float m0 = importance[i0];
        float f0 = feats[(size_t)i0 * CIN + c];
        float* bp = S0 + (n0 - p0) * (2 * KC * CIN) + q0 * CIN + c;
        atomicAdd(bp, f0);
        atomicAdd(bp + KC * CIN, f0 * m0);
        if (c == 0) atomicAdd(&sImp[n0 - p0], m0);
    }
    __syncthreads();

    const int wave = tid >> 6;
    const int lane = tid & 63;
    const int f    = lane & 31;
    const int h    = lane >> 5;
#pragma unroll
    for (int rep = 0; rep < 2; ++rep) {
        const int slot = wave * 2 + rep;
        const int n    = p0 + slot;
        if (n >= nout) break;
        float impTot = sImp[slot];
        float denom  = impTot > 0.f ? impTot : 1.f;
        const float* Sbase = &sS[slot][(f < CA) ? 0 : 1][0];
        const float* Wbase = sW + f * WSTR;
        float acc = 0.f;
#pragma unroll
        for (int k = 0; k < KC; ++k) {
            int off = k * CIN + h * 16;
#pragma unroll
            for (int j = 0; j < 16; ++j) acc = fmaf(Sbase[off + j], Wbase[off + j], acc);
        }
        float tot = acc + __shfl_xor(acc, 32, 64);
        if (h == 0) {
            float res = (f < CA) ? (tot + ba[f]) : (tot / denom + bb[f - CA]);
            outf[(size_t)n * COUT + f] = fmaxf(res, 0.f);
        }
        if (lane == 0) outimp[n] = impTot;
    }
}

// ---------------------------------------------------------------------------
extern "C" void kernel_launch(void* const* d_in, const int* in_sizes, int n_in,
                              void* d_out, int out_size, void* d_ws, size_t ws_size,
                              hipStream_t stream) {
    const float* feats      = (const float*)d_in[0];
    const float* importance = (const float*)d_in[1];
    const float* Wa         = (const float*)d_in[2];
    const float* ba         = (const float*)d_in[3];
    const float* Wb         = (const float*)d_in[4];
    const float* bb         = (const float*)d_in[5];
    const int*   nidx       = (const int*)d_in[6];
    const int*   nkidx      = (const int*)d_in[7];
    const int*   noidx      = (const int*)d_in[8];

    const int E    = in_sizes[6];
    const int nout = out_size / (COUT + 1);

    float* outf   = (float*)d_out;
    float* outimp = outf + (size_t)nout * COUT;

    // ws: S bf16 [nout*576] | impAcc [nout] | Wc [288*32] | rp [nout+1] | imp_e [E]
    const size_t off_imp = ((size_t)nout * SPP * sizeof(__hip_bfloat16) + 255) & ~(size_t)255;
    const size_t off_wc  = (off_imp + (size_t)nout * sizeof(float) + 255) & ~(size_t)255;
    const size_t off_rp  = (off_wc + (size_t)KCC * COUT * sizeof(float) + 255) & ~(size_t)255;
    const size_t off_ie  = (off_rp + (size_t)(nout + 1) * sizeof(int) + 255) & ~(size_t)255;
    const size_t need    = off_ie + (size_t)E * sizeof(float);

    if (ws_size >= need) {
        __hip_bfloat16* S = (__hip_bfloat16*)d_ws;
        float* impAcc = (float*)((char*)d_ws + off_imp);
        float* Wc     = (float*)((char*)d_ws + off_wc);
        int*   rp     = (int*)((char*)d_ws + off_rp);
        float* imp_e  = (float*)((char*)d_ws + off_ie);

        prep<<<(E + 255) / 256, 256, 0, stream>>>(
            noidx, nidx, importance, Wa, Wb, rp, imp_e, Wc, E, nout);
        accum_y<<<2048, 256, 0, stream>>>(
            feats, imp_e, nidx, nkidx, rp, S, impAcc, nout);
        epilogue_g<<<(nout + 255) / 256, 256, 0, stream>>>(
            S, impAcc, Wc, ba, bb, outf, outimp, nout);
    } else {
        int*   rp = (int*)d_ws;
        size_t rp_bytes = ((size_t)(nout + 1) * sizeof(int) + 255) & ~(size_t)255;
        float* Wt = (float*)((char*)d_ws + rp_bytes);

        build_rowptr_fb<<<(E + 255) / 256, 256, 0, stream>>>(noidx, rp, E, nout);
        pack_weights_fkc<<<(COUT * KC * CIN + 255) / 256, 256, 0, stream>>>(Wa, Wb, Wt);
        fused_block<<<(nout + PPB - 1) / PPB, TPB, 0, stream>>>(
            feats, importance, Wt, ba, bb, nidx, nkidx, noidx, rp,
            outf, outimp, nout);
    }
}